// Round 5
// baseline (154.530 us; speedup 1.0000x reference)
//
#include <hip/hip_runtime.h>
#include <stdint.h>

#define N_ROWS 4096
#define Z_DIM  2048
#define TOT    8192           // 2N rows of reps
#define TILE   128
#define RBYTES (Z_DIM / 2)    // 1024 B per fp4 row
#define BKE    128            // K elements per staging round
#define KBYT   (BKE / 2)      // 64 B per row per staging round
#define NITER  (Z_DIM / BKE)  // 16
#define NT     (TOT / TILE)   // 64 tile-columns
#define NBLK   (NT * (NT + 1) / 2)   // 2080 triangular blocks (2080%8==0)
#define OPB    (TILE * KBYT)  // 8192 B per operand per K-step
#define INV_T  2.0f           // 1/temperature
#define SCL4   64.0f          // fp4 pre-scale; logits = acc * INV_T / SCL4^2

typedef __attribute__((ext_vector_type(4))) int   intx4;
typedef __attribute__((ext_vector_type(8))) int   intx8;
typedef __attribute__((ext_vector_type(4))) float floatx4;

#define GLOAD16(g, l)                                                   \
    __builtin_amdgcn_global_load_lds(                                   \
        (const __attribute__((address_space(1))) unsigned int*)(g),     \
        (__attribute__((address_space(3))) unsigned int*)(l), 16, 0, 0)

// branchless f32 -> fp4 e2m1 code (round to nearest level)
// levels: 0,0.5,1,1.5,2,3,4,6 ; thresholds at midpoints
__device__ __forceinline__ unsigned int f2fp4(float v) {
    float a = fabsf(v);
    unsigned int c = (a >= 0.25f) + (a >= 0.75f) + (a >= 1.25f) + (a >= 1.75f)
                   + (a >= 2.5f)  + (a >= 3.5f)  + (a >= 5.0f);
    return c | (v < 0.f ? 8u : 0u);
}

// ---------------- kernel 1: row-normalize to fp4(e2m1, x64), pos, zero rowsum
__global__ __launch_bounds__(256) void normalize_kernel(
    const float* __restrict__ z1, const float* __restrict__ z2,
    unsigned char* __restrict__ reps, float* __restrict__ pos,
    float* __restrict__ rowsum)
{
    const int row  = blockIdx.x;          // 0..4095
    const int tid  = threadIdx.x;         // 0..255, 8 floats each
    const int lane = tid & 63, wave = tid >> 6;

    if (row < TOT / 256) rowsum[row * 256 + tid] = 0.f;   // fold in memset

    const float4* p1 = (const float4*)(z1 + (size_t)row * Z_DIM);
    const float4* p2 = (const float4*)(z2 + (size_t)row * Z_DIM);
    float4 x0 = p1[tid * 2], x1 = p1[tid * 2 + 1];
    float4 y0 = p2[tid * 2], y1 = p2[tid * 2 + 1];

    float s1 = x0.x*x0.x + x0.y*x0.y + x0.z*x0.z + x0.w*x0.w
             + x1.x*x1.x + x1.y*x1.y + x1.z*x1.z + x1.w*x1.w;
    float s2 = y0.x*y0.x + y0.y*y0.y + y0.z*y0.z + y0.w*y0.w
             + y1.x*y1.x + y1.y*y1.y + y1.z*y1.z + y1.w*y1.w;
    float dd = x0.x*y0.x + x0.y*y0.y + x0.z*y0.z + x0.w*y0.w
             + x1.x*y1.x + x1.y*y1.y + x1.z*y1.z + x1.w*y1.w;

    #pragma unroll
    for (int m = 1; m < 64; m <<= 1) {
        s1 += __shfl_xor(s1, m);
        s2 += __shfl_xor(s2, m);
        dd += __shfl_xor(dd, m);
    }
    __shared__ float red[3][4];
    if (lane == 0) { red[0][wave] = s1; red[1][wave] = s2; red[2][wave] = dd; }
    __syncthreads();
    s1 = red[0][0] + red[0][1] + red[0][2] + red[0][3];
    s2 = red[1][0] + red[1][1] + red[1][2] + red[1][3];
    dd = red[2][0] + red[2][1] + red[2][2] + red[2][3];

    const float inv1 = rsqrtf(s1), inv2 = rsqrtf(s2);
    if (tid == 0) {
        float p = dd * inv1 * inv2 * INV_T;   // pos in full fp32 precision
        pos[row] = p;
        pos[row + N_ROWS] = p;
    }

    // fp4 encode of (normalized * 64): sigma ~1.4, range to ~6 (rare clip).
    // elem k -> byte k/2, LOW nibble = even k.
    const float a = inv1 * SCL4, b = inv2 * SCL4;
    unsigned int pa =  f2fp4(x0.x * a)        | (f2fp4(x0.y * a) << 4)
                    | (f2fp4(x0.z * a) << 8)  | (f2fp4(x0.w * a) << 12)
                    | (f2fp4(x1.x * a) << 16) | (f2fp4(x1.y * a) << 20)
                    | (f2fp4(x1.z * a) << 24) | (f2fp4(x1.w * a) << 28);
    unsigned int pb =  f2fp4(y0.x * b)        | (f2fp4(y0.y * b) << 4)
                    | (f2fp4(y0.z * b) << 8)  | (f2fp4(y0.w * b) << 12)
                    | (f2fp4(y1.x * b) << 16) | (f2fp4(y1.y * b) << 20)
                    | (f2fp4(y1.z * b) << 24) | (f2fp4(y1.w * b) << 28);
    *(unsigned int*)(reps + (size_t)row * RBYTES + tid * 4) = pa;
    *(unsigned int*)(reps + (size_t)(N_ROWS + row) * RBYTES + tid * 4) = pb;
}

// ---------------- kernel 2: triangular S = reps@reps^T, MX-fp4 K=128 --------
// Round-4 structure (128x128 tile, 2x2 waves, conflict-free (row>>1)&3
// swizzle, counted vmcnt + raw barrier, XCD-chunked block swizzle) with the
// occupancy pushed from 3 to 4 blocks/CU:
//  (a) asymmetric buffers: 3x A (24 KiB) + 2x B (16 KiB) = 40 KiB LDS
//      (= 160/4 exactly). Lookahead A=2 steps, B=1 step. Per-step issue
//      order B(i+1) THEN A(i+2) makes the per-step wait exactly vmcnt(2):
//      queue at step-i wait = [A(i)x2, B(i)x2, A(i+1)x2] -> complete 4,
//      leave A(i+1) in flight. Never drains to 0 mid-loop.
//      Write hazards: LB[(i+1)&1] / LA[(i+2)%3] were last read at step i-1,
//      done before this step's barrier (round-4 proof shape).
//  (b) register diet + __launch_bounds__(256,4): stream A-frags through one
//      a8, ds_read straight into the low quad of persistent intx8 frags
//      (uppers zeroed once; fp4 FMT reads only v[0:3] anyway), derive +64-row
//      staging addrs from one base (the (r>>1)&3 key is invariant under +64).
__global__ __launch_bounds__(256, 4) void simclr_gemm(
    const unsigned char* __restrict__ reps, float* __restrict__ rowsum)
{
    __shared__ __align__(16) unsigned char LA[3][OPB];   // 24 KiB
    __shared__ __align__(16) unsigned char LB[2][OPB];   // 16 KiB

    // XCD-aware chunked swizzle, then decode to lower-triangle (r >= c)
    const int bid = blockIdx.x;
    const int t = (bid & 7) * (NBLK / 8) + (bid >> 3);
    int r = (int)((sqrtf(8.0f * (float)t + 1.0f) - 1.0f) * 0.5f);
    while ((r + 1) * (r + 2) / 2 <= t) ++r;
    while (r * (r + 1) / 2 > t) --r;
    const int bi = t - r * (r + 1) / 2;   // <= bj
    const int bj = r;
    const bool diag = (bi == bj);

    const int tid  = threadIdx.x;
    const int lane = tid & 63, wave = tid >> 6;
    const int wr = wave >> 1, wc = wave & 1;       // 2x2 waves over 128x128
    const int quad = lane >> 4, l16 = lane & 15;
    const int sw   = (l16 >> 1) & 3;               // read-side XOR swizzle key
    const int row0 = bi * TILE, col0 = bj * TILE;

    floatx4 acc[4][4];
    #pragma unroll
    for (int i = 0; i < 4; ++i)
        #pragma unroll
        for (int j = 0; j < 4; ++j)
            acc[i][j] = floatx4{0.f, 0.f, 0.f, 0.f};

    // staging: 512 chunks of 16B per operand (128 rows x 4 chunks); thread
    // handles chunks tid and tid+256. LDS slot c holds global chunk
    // ((c&3) ^ (((c>>2)>>1)&3)) of row c>>2. Chunk tid+256 = same k-slot,
    // +64 rows -> address derived as +64*RBYTES, LDS offset +4096.
    const int r0s = tid >> 2, k0s = (tid & 3) ^ ((r0s >> 1) & 3);
    const unsigned char* gA0 = reps + (size_t)(row0 + r0s) * RBYTES + k0s * 16;
    const unsigned char* gB0 = reps + (size_t)(col0 + r0s) * RBYTES + k0s * 16;
    const int o0 = tid * 16;     // [0,4096); second chunk at o0+4096

    // persistent fragments: uppers zeroed ONCE (fp4 FMT uses v[0:3] only)
    intx8 a8 = intx8{0, 0, 0, 0, 0, 0, 0, 0};
    intx8 b8[4];
    #pragma unroll
    for (int j = 0; j < 4; ++j) b8[j] = intx8{0, 0, 0, 0, 0, 0, 0, 0};

    // prologue: A0, B0, A1 (6 loads/thread in flight), in this queue order
    GLOAD16(gA0,                     &LA[0][o0]);
    GLOAD16(gA0 + 64 * RBYTES,       &LA[0][o0 + 4096]);
    GLOAD16(gB0,                     &LB[0][o0]);
    GLOAD16(gB0 + 64 * RBYTES,       &LB[0][o0 + 4096]);
    GLOAD16(gA0 + KBYT,              &LA[1][o0]);
    GLOAD16(gA0 + 64 * RBYTES + KBYT, &LA[1][o0 + 4096]);

    int bufA = 0;
    #pragma unroll 1
    for (int i = 0; i < NITER; ++i) {
        // complete A(i)+B(i) (oldest 4); leave A(i+1) (2) in flight
        if (i + 1 < NITER) asm volatile("s_waitcnt vmcnt(2)" ::: "memory");
        else               asm volatile("s_waitcnt vmcnt(0)" ::: "memory");
        __builtin_amdgcn_s_barrier();
        asm volatile("" ::: "memory");

        // issue B(i+1) FIRST, then A(i+2) -- queue order feeds vmcnt(2)
        if (i + 1 < NITER) {
            const size_t ko = (size_t)(i + 1) * KBYT;
            unsigned char* d = &LB[(i + 1) & 1][0];
            GLOAD16(gB0 + ko,               d + o0);
            GLOAD16(gB0 + 64 * RBYTES + ko, d + o0 + 4096);
        }
        asm volatile("" ::: "memory");
        if (i + 2 < NITER) {
            const size_t ko = (size_t)(i + 2) * KBYT;
            int pf = bufA + 2; if (pf >= 3) pf -= 3;
            unsigned char* d = &LA[pf][0];
            GLOAD16(gA0 + ko,               d + o0);
            GLOAD16(gA0 + 64 * RBYTES + ko, d + o0 + 4096);
        }

        const unsigned char* Ab = &LA[bufA][0];
        const unsigned char* Bb = &LB[i & 1][0];

        // B frags: ds_read_b128 into low quad of persistent b8[j]
        #pragma unroll
        for (int j = 0; j < 4; ++j)
            *(intx4*)&b8[j] =
                *(const intx4*)&Bb[(wc * 64 + j * 16 + l16) * KBYT
                                   + ((quad ^ sw) << 4)];

        __builtin_amdgcn_s_setprio(1);
        #pragma unroll
        for (int fi = 0; fi < 4; ++fi) {
            *(intx4*)&a8 =
                *(const intx4*)&Ab[(wr * 64 + fi * 16 + l16) * KBYT
                                   + ((quad ^ sw) << 4)];
            #pragma unroll
            for (int j = 0; j < 4; ++j)
                acc[fi][j] = __builtin_amdgcn_mfma_scale_f32_16x16x128_f8f6f4(
                    a8, b8[j], acc[fi][j],
                    4, 4,                      // cbsz=fp4(A), blgp=fp4(B)
                    0, 0x7F7F7F7Fu,            // scale_a = 1.0 (E8M0)
                    0, 0x7F7F7F7Fu);           // scale_b = 1.0
        }
        __builtin_amdgcn_s_setprio(0);
        bufA = (bufA == 2) ? 0 : bufA + 1;
    }

    // Epilogue: C/D layout col = lane&15, row = quad*4 + reg.
    // logit = acc * INV_T / SCL4^2; |logit| <= 2 so plain exp-sum is safe.
    const float descale = INV_T / (SCL4 * SCL4);   // 1/2048
    float scol[4] = {0.f, 0.f, 0.f, 0.f};
    #pragma unroll
    for (int fi = 0; fi < 4; ++fi) {
        const int rbase = row0 + wr * 64 + fi * 16 + quad * 4;
        float srow[4] = {0.f, 0.f, 0.f, 0.f};
        #pragma unroll
        for (int j = 0; j < 4; ++j) {
            const int c = col0 + wc * 64 + j * 16 + l16;
            #pragma unroll
            for (int rr = 0; rr < 4; ++rr) {
                float e = __expf(acc[fi][j][rr] * descale);
                if (diag && (rbase + rr == c)) e = 0.f;  // exclude self-sim
                srow[rr] += e;
                scol[j]  += e;
            }
        }
        #pragma unroll
        for (int rr = 0; rr < 4; ++rr) {
            #pragma unroll
            for (int m = 1; m < 16; m <<= 1) srow[rr] += __shfl_xor(srow[rr], m);
        }
        if (l16 == 0) {
            #pragma unroll
            for (int rr = 0; rr < 4; ++rr)
                atomicAdd(&rowsum[rbase + rr], srow[rr]);
        }
    }
    if (!diag) {   // symmetry credit: column sums -> mirrored rows
        #pragma unroll
        for (int j = 0; j < 4; ++j) {
            scol[j] += __shfl_xor(scol[j], 16);
            scol[j] += __shfl_xor(scol[j], 32);
        }
        if (quad == 0) {
            #pragma unroll
            for (int j = 0; j < 4; ++j)
                atomicAdd(&rowsum[col0 + wc * 64 + j * 16 + l16], scol[j]);
        }
    }
}

// ---------------- kernel 3: mean(log(rowsum) - pos) ----------------
__global__ __launch_bounds__(1024) void finalize_kernel(
    const float* __restrict__ rowsum, const float* __restrict__ pos,
    float* __restrict__ out)
{
    const int tid = threadIdx.x;
    const int lane = tid & 63, wave = tid >> 6;
    float s = 0.f;
    for (int r = tid; r < TOT; r += 1024) s += logf(rowsum[r]) - pos[r];
    #pragma unroll
    for (int m = 1; m < 64; m <<= 1) s += __shfl_xor(s, m);
    __shared__ float red[16];
    if (lane == 0) red[wave] = s;
    __syncthreads();
    if (tid == 0) {
        float t = 0.f;
        #pragma unroll
        for (int w = 0; w < 16; ++w) t += red[w];
        out[0] = t * (1.0f / TOT);
    }
}

extern "C" void kernel_launch(void* const* d_in, const int* in_sizes, int n_in,
                              void* d_out, int out_size, void* d_ws, size_t ws_size,
                              hipStream_t stream)
{
    const float* z1 = (const float*)d_in[0];
    const float* z2 = (const float*)d_in[1];
    float* out = (float*)d_out;

    char* w = (char*)d_ws;
    unsigned char* reps = (unsigned char*)w;                 // 8 MiB fp4 [8192][1024B]
    float* pos    = (float*)(w + (size_t)TOT * RBYTES);      // 32 KiB
    float* rowsum = pos + TOT;                               // 32 KiB

    normalize_kernel<<<N_ROWS, 256, 0, stream>>>(z1, z2, reps, pos, rowsum);
    simclr_gemm<<<NBLK, 256, 0, stream>>>(reps, rowsum);
    finalize_kernel<<<1, 1024, 0, stream>>>(rowsum, pos, out);
}